// Round 14
// baseline (19.455 us; speedup 1.0000x reference)
//
#include <hip/hip_runtime.h>

// out[b, f*64+n] = sum_c sum_j x[b, c*64+j] * w[f, c, (n-j)&63]
// R14: halve L2 A-traffic. R12/R13 established: gemm = serial sum with
// A-delivery ~4us because all 64 same-q blocks re-read the same A-slice
// (A independent of f) -> 16 MB/XCD/pass. Fix: 2 f per block.
// Block = 32 rows x 128 cols, grid 256 = 8 q x 32 fg, q = bid&7 (XCD-local
// A-slice). 16 waves = 2 colgroups(f) x 8 kgroups(8 c). Tables 2f x 64c =
// 147456 B LDS. R13's asm depth-2 counted-vmcnt A-prefetch + STEP retained.
// Epilogue: flat 2-barrier 8-way kgroup reduce.

#define KDIM 4096

typedef __attribute__((ext_vector_type(8)))  short s16x8;
typedef __attribute__((ext_vector_type(4)))  float f32x4;
typedef __attribute__((ext_vector_type(16))) float f32x16;
typedef unsigned short u16;

__device__ __forceinline__ u16 f2bf(float f) {
  unsigned int u = __float_as_uint(f);
  u += 0x7FFF + ((u >> 16) & 1);   // round-to-nearest-even
  return (u16)(u >> 16);
}

// ---- pack x (fp32 256x4096) -> Xp bf16 in 32x32x16-A-fragment order ----
// (byte-identical to R7; Xp layout unchanged)
__global__ __launch_bounds__(256) void pack_kernel(const float* __restrict__ x,
                                                   u16* __restrict__ Xp) {
  __shared__ __align__(16) u16 tile[32 * 264];
  const int tid = threadIdx.x;
  const int rg  = blockIdx.x >> 4;
  const int cg  = blockIdx.x & 15;

  #pragma unroll
  for (int i = 0; i < 4; ++i) {
    int g    = i * 2048 + tid * 8;
    int row  = g >> 8;
    int kloc = g & 255;
    const float4* src = (const float4*)(x + (size_t)(rg * 32 + row) * 4096 + cg * 256 + kloc);
    float4 v0 = src[0], v1 = src[1];
    union { u16 u[8]; uint4 v; } o;
    o.u[0] = f2bf(v0.x); o.u[1] = f2bf(v0.y); o.u[2] = f2bf(v0.z); o.u[3] = f2bf(v0.w);
    o.u[4] = f2bf(v1.x); o.u[5] = f2bf(v1.y); o.u[6] = f2bf(v1.z); o.u[7] = f2bf(v1.w);
    *(uint4*)(tile + row * 264 + kloc) = o.v;
  }
  __syncthreads();

  const int lane = tid & 63;
  const int fw   = tid >> 6;
  #pragma unroll
  for (int i = 0; i < 4; ++i) {
    int fidx = i * 4 + fw;
    int cl   = fidx >> 2;
    int kk   = fidx & 3;
    int c    = cg * 4 + cl;
    uint4 v = *(const uint4*)(tile + (lane & 31) * 264 + cl * 64 + kk * 16 + (lane >> 5) * 8);
    size_t u = ((size_t)((c * 8 + rg) * 4 + kk) << 6) + lane;
    *(uint4*)(Xp + (u << 3)) = v;
  }
}

// ---- fused circulant GEMM: 2 f per block, 8-way K-group split ----
__global__ __launch_bounds__(1024, 4) void gemm_f2(const u16* __restrict__ Xp,
                                                   const float* __restrict__ w,
                                                   float* __restrict__ out) {
  extern __shared__ __align__(16) char pool[];   // 147456 B
  u16*   tab = (u16*)pool;                       // [2f][64c][576] u16
  float* red = (float*)pool;                     // epilogue: 16 slots x 8 KB

  const int tid   = threadIdx.x;
  const int lane  = tid & 63;
  const int wid   = tid >> 6;        // 0..15 = kg*2 + cg
  const int cg    = wid & 1;         // which f of the pair
  const int kg    = wid >> 1;        // K-group: c in [kg*8, kg*8+8)
  const int l31   = lane & 31;
  const int lh    = lane >> 5;
  const int q     = blockIdx.x & 7;  // 32-row group; == XCD id (A L2-local)
  const int fg    = blockIdx.x >> 3; // f-pair index (0..31)

  // build 128 tables: wave wid builds t = wid*8 .. wid*8+7; t = fidx*64 + c
  #pragma unroll
  for (int j = 0; j < 8; ++j) {
    int t    = wid * 8 + j;
    int fidx = t >> 6;
    int c    = t & 63;
    u16 bv = f2bf(w[((size_t)(fg * 2 + fidx) << 12) + (c << 6) + lane]);
    u16* T = tab + t * 576;
    #pragma unroll
    for (int m = 0; m < 8; ++m) {
      int i = (-(lane + m)) & 63;    // C_m[i] = w[(-i-m)&63]
      T[m * 72 + i] = bv;
    }
  }

  int bofs0, bofs1, bofs2, bofs3;
  {
    int i0;
    i0 = (lh * 8 - l31)      & 63; bofs0 = (i0 & 7) * 71 + i0;
    i0 = (lh * 8 - l31 - 16) & 63; bofs1 = (i0 & 7) * 71 + i0;
    i0 = (lh * 8 - l31 - 32) & 63; bofs2 = (i0 & 7) * 71 + i0;
    i0 = (lh * 8 - l31 - 48) & 63; bofs3 = (i0 & 7) * 71 + i0;
  }

  // A-frag base: u16 idx = ((c*8+q)*4+kk)*512 + lane*8 = c*16384 + q*2048 + ..
  // wave starts at c = kg*8; per-step (one c) stride = 16384 u16 = 32 KB
  const u16* abase = Xp + ((size_t)kg * 8 * 16384 + q * 2048 + lane * 8);
  const u16* tabf  = tab + cg * 36864;   // this wave's f-table block (64*576)

  s16x8 A0_0, A0_1, A0_2, A0_3;
  s16x8 A1_0, A1_1, A1_2, A1_3;
  s16x8 A2_0, A2_1, A2_2, A2_3;

  #define ALOAD(SET, T)                                                   \
    { const u16* nb_ = abase + (size_t)(T) * 16384;                       \
      asm volatile("global_load_dwordx4 %0, %4, off\n\t"                  \
                   "global_load_dwordx4 %1, %4, off offset:1024\n\t"      \
                   "global_load_dwordx4 %2, %4, off offset:2048\n\t"      \
                   "global_load_dwordx4 %3, %4, off offset:3072"          \
                   : "=&v"(A##SET##_0), "=&v"(A##SET##_1),                \
                     "=&v"(A##SET##_2), "=&v"(A##SET##_3)                 \
                   : "v"(nb_)); }

  #define WAITV_(N) asm volatile("s_waitcnt vmcnt(" #N ")")
  #define WAITV(N)  WAITV_(N)

  f32x16 acc0 = {}, acc1 = {};

  __syncthreads();                   // tables visible; compiler loads drained

  ALOAD(0, 0)                        // prefetch c-steps 0,1 (8 outstanding)
  ALOAD(1, 1)

  #define STEP(T, CUR, PRE, DOPRE, WN)                                        \
    {                                                                         \
      if (DOPRE) ALOAD(PRE, (T) + 2)                                          \
      const u16* Tb = tabf + (kg * 8 + (T)) * 576;                            \
      s16x8 b0 = *(const s16x8*)(Tb + bofs0);                                 \
      s16x8 b1 = *(const s16x8*)(Tb + bofs1);                                 \
      s16x8 b2 = *(const s16x8*)(Tb + bofs2);                                 \
      s16x8 b3 = *(const s16x8*)(Tb + bofs3);                                 \
      WAITV(WN);                                                              \
      __builtin_amdgcn_sched_barrier(0);                                      \
      acc0 = __builtin_amdgcn_mfma_f32_32x32x16_bf16(A##CUR##_0, b0, acc0, 0, 0, 0); \
      acc1 = __builtin_amdgcn_mfma_f32_32x32x16_bf16(A##CUR##_0, b2, acc1, 0, 0, 0); \
      acc0 = __builtin_amdgcn_mfma_f32_32x32x16_bf16(A##CUR##_1, b3, acc0, 0, 0, 0); \
      acc1 = __builtin_amdgcn_mfma_f32_32x32x16_bf16(A##CUR##_1, b1, acc1, 0, 0, 0); \
      acc0 = __builtin_amdgcn_mfma_f32_32x32x16_bf16(A##CUR##_2, b2, acc0, 0, 0, 0); \
      acc1 = __builtin_amdgcn_mfma_f32_32x32x16_bf16(A##CUR##_2, b0, acc1, 0, 0, 0); \
      acc0 = __builtin_amdgcn_mfma_f32_32x32x16_bf16(A##CUR##_3, b1, acc0, 0, 0, 0); \
      acc1 = __builtin_amdgcn_mfma_f32_32x32x16_bf16(A##CUR##_3, b3, acc1, 0, 0, 0); \
    }

  STEP(0, 0, 2, 1, 8)
  STEP(1, 1, 0, 1, 8)
  STEP(2, 2, 1, 1, 8)
  STEP(3, 0, 2, 1, 8)
  STEP(4, 1, 0, 1, 8)
  STEP(5, 2, 1, 1, 8)
  STEP(6, 0, 2, 0, 4)
  STEP(7, 1, 2, 0, 0)

  // ---- flattened epilogue: 2 barriers; 8-way kgroup reduce per cg ----
  __syncthreads();                   // all table reads done; reuse pool
  {
    float* slot = red + (cg * 8 + kg) * 2048;   // 8 KB per wave
    #pragma unroll
    for (int i = 0; i < 4; ++i) {
      f32x4 v0 = {acc0[4*i], acc0[4*i+1], acc0[4*i+2], acc0[4*i+3]};
      f32x4 v1 = {acc1[4*i], acc1[4*i+1], acc1[4*i+2], acc1[4*i+3]};
      *(f32x4*)(slot + ((i)     * 64 + lane) * 4) = v0;
      *(f32x4*)(slot + ((i + 4) * 64 + lane) * 4) = v1;
    }
  }
  __syncthreads();
  {
    const int rcg = tid >> 9;            // which f of the pair we reduce
    const int ii  = (tid >> 6) & 7;      // 0..3 acc0 quads, 4..7 acc1 quads
    const int sl  = tid & 63;            // source lane
    f32x4 s = {};
    #pragma unroll
    for (int k = 0; k < 8; ++k)
      s += *(const f32x4*)(red + (size_t)(rcg * 8 + k) * 2048 + (ii * 64 + sl) * 4);
    // C/D (m74/m101): col = lane&31, row = (reg&3)+8*(reg>>2)+4*(lane>>5)
    const int col  = ((fg * 2 + rcg) << 6) + (ii >> 2) * 32 + (sl & 31);
    const int rowb = q * 32 + 8 * (ii & 3) + 4 * (sl >> 5);
    #pragma unroll
    for (int e = 0; e < 4; ++e)
      out[(size_t)(rowb + e) * 4096 + col] = s[e];
  }
}

extern "C" void kernel_launch(void* const* d_in, const int* in_sizes, int n_in,
                              void* d_out, int out_size, void* d_ws, size_t ws_size,
                              hipStream_t stream) {
  const float* x = (const float*)d_in[0];    // (256, 4096) fp32
  const float* w = (const float*)d_in[1];    // (64, 64, 64) fp32
  float* out = (float*)d_out;                // (256, 4096) fp32

  u16* Xp = (u16*)d_ws;                      // 2 MB packed bf16 X

  pack_kernel<<<128, 256, 0, stream>>>(x, Xp);
  gemm_f2<<<256, 1024, 147456, stream>>>(Xp, w, out);
}